// Round 9
// baseline (492.597 us; speedup 1.0000x reference)
//
#include <hip/hip_runtime.h>

// WaveRNN: damped 2D wave equation, B=16, T=256, 256x256 grid, 3 probes.
// 8 slabs/batch (128 WGs x 512 thr, cooperative). Wave w owns rows s*32+4w..+3,
// lane l owns cols 4l..4l+3 (4x4 register tile).
// FULLY CHUNKED K=4 temporal blocking, NO barriers in the main loop:
// every wave keeps 4 ghost rows on EACH side (both time levels) in registers
// and steps them redundantly (shrinking trapezoid). All synchronization is
// once per 4 steps:
//   intra-WG : single-buffered LDS halo slot per wave (8 rows: h1 r0-3,
//              h2 r0-3) + chunk tag (vals -> lgkmcnt(0) -> tag; in-order DS
//              per wave => tag-visible implies vals-visible) + read-ack so a
//              producer never overwrites an unread slot.
//   inter-WG : tagged 8-byte {chunk,value} packets, relaxed agent-scope
//              atomics, parity double-buffered (proven R3/R7 protocol).
// Work is balanced: every wave does 4 own rows + up to 3+3 shrinking ghost
// rows per substep. Ghost coefficients come from an 80 KB LDS table; owner
// coefficients are read from the SAME table rows, so ghost arithmetic is
// bitwise-identical to the owner's (same values, same fma order).

#define B_    16
#define T_    256
#define NY    256
#define NP    3
#define NSLAB 8
#define WAVES 8
#define THREADS 512
#define NIF   (NSLAB - 1)
#define KCH   4
#define NCHUNK (T_ / KCH)

// [batch][iface][side][parity][rowfield 0..7][packed col = j*64 + lane]
// iface i joins slab i (upper) and slab i+1 (lower).
// side0 = slab i's bottom 4 rows; side1 = slab i+1's top 4 rows.
// rowfield 0..3 = h1 rows (level 4c), 4..7 = h2 rows (level 4c-1).
__device__ uint64_t g_halo[B_][NIF][2][2][8][NY];

__global__ void reset_halo()
{
    const int n = B_ * NIF * 2 * 2 * 8 * NY;
    int i = blockIdx.x * blockDim.x + threadIdx.x;
    if (i < n) (&g_halo[0][0][0][0][0][0])[i] = 0ull;   // tag0 = chunk-0 zeros
}

#define PACK(tag, f) (((uint64_t)(uint32_t)(tag) << 32) | (uint64_t)__float_as_uint(f))

#define GPOLL32(GA, GB, SIDE, IFACE, TAG) do { \
    uint64_t* gp_ = &g_halo[b][IFACE][SIDE][(TAG) & 1][0][0]; \
    uint64_t vv_[8][4]; bool ok_; \
    do { \
        ok_ = true; \
        _Pragma("unroll") for (int rf = 0; rf < 8; ++rf) \
            _Pragma("unroll") for (int j = 0; j < 4; ++j) \
                vv_[rf][j] = __hip_atomic_load(gp_ + rf * NY + j * 64 + l, \
                                               __ATOMIC_RELAXED, __HIP_MEMORY_SCOPE_AGENT); \
        _Pragma("unroll") for (int rf = 0; rf < 8; ++rf) \
            _Pragma("unroll") for (int j = 0; j < 4; ++j) \
                ok_ = ok_ && ((uint32_t)(vv_[rf][j] >> 32) == (uint32_t)(TAG)); \
    } while (!ok_); \
    _Pragma("unroll") for (int i = 0; i < 4; ++i) \
        _Pragma("unroll") for (int j = 0; j < 4; ++j) { \
            GA[i][j] = __uint_as_float((uint32_t)vv_[i][j]); \
            GB[i][j] = __uint_as_float((uint32_t)vv_[4 + i][j]); \
        } \
} while (0)

#define GPUB32(SIDE, IFACE, TAG1, HH1, HH2) do { \
    uint64_t* gp_ = &g_halo[b][IFACE][SIDE][(TAG1) & 1][0][0]; \
    _Pragma("unroll") for (int i = 0; i < 4; ++i) \
        _Pragma("unroll") for (int j = 0; j < 4; ++j) { \
            __hip_atomic_store(gp_ + i * NY + j * 64 + l, PACK(TAG1, HH1[i][j]), \
                               __ATOMIC_RELAXED, __HIP_MEMORY_SCOPE_AGENT); \
            __hip_atomic_store(gp_ + (4 + i) * NY + j * 64 + l, PACK(TAG1, HH2[i][j]), \
                               __ATOMIC_RELAXED, __HIP_MEMORY_SCOPE_AGENT); \
        } \
} while (0)

// hn = h2 + TC*(h1-h2) + CC*(s4 - 4*h1)   [c1*c2 == 2*c1 - 1]
#define ROWC(HA, HB, r, UPA, DNA) do { \
    float lf_ = __shfl_up(HA[r][3], 1, 64); \
    float rt_ = __shfl_down(HA[r][0], 1, 64); \
    if (l == 0)  lf_ = 0.f; \
    if (l == 63) rt_ = 0.f; \
    _Pragma("unroll") for (int j = 0; j < 4; ++j) { \
        const float lv_ = (j == 0) ? lf_ : HA[r][j - 1]; \
        const float rv_ = (j == 3) ? rt_ : HA[r][j + 1]; \
        const float s4_ = (UPA[j] + DNA[j]) + (lv_ + rv_); \
        const float d_  = HA[r][j] - HB[r][j]; \
        const float e_  = fmaf(-4.0f, HA[r][j], s4_); \
        float v_ = fmaf(CCr[r][j], e_, HB[r][j]); \
        v_ = fmaf(TCr[r][j], d_, v_); \
        HB[r][j] = v_; \
    } \
} while (0)

#define SRCP(HB, r, TT) do { \
    if (srcHere && src_r == (r)) { \
        _Pragma("unroll") for (int j = 0; j < 4; ++j) \
            if (src_c == j) HB[r][j] += xbuf[TT]; \
    } \
    _Pragma("unroll") for (int qq = 0; qq < NP; ++qq) { \
        if (pHere[qq] && pr[qq] == (r)) { \
            float v_ = 0.f; \
            _Pragma("unroll") for (int j = 0; j < 4; ++j) \
                if (pc[qq] == j) v_ = HB[r][j]; \
            out[((size_t)b * T_ + (TT)) * NP + qq] = v_; \
        } \
    } \
} while (0)

// up-ghost row I_ (global row r0-4+I_, coef table row w4+I_); valid iff I_>=K_+1
#define GUP(GA, GB, HA, I_, K_, TT) do { \
    if ((I_) >= (K_) + 1) { \
        const float4 tc4_ = *reinterpret_cast<const float4*>(&ldsTC[w4 + (I_)][y0]); \
        const float4 cc4_ = *reinterpret_cast<const float4*>(&ldsCC[w4 + (I_)][y0]); \
        const float tcv_[4] = {tc4_.x, tc4_.y, tc4_.z, tc4_.w}; \
        const float ccv_[4] = {cc4_.x, cc4_.y, cc4_.z, cc4_.w}; \
        float lf_ = __shfl_up(GA[I_][3], 1, 64); \
        float rt_ = __shfl_down(GA[I_][0], 1, 64); \
        if (l == 0)  lf_ = 0.f; \
        if (l == 63) rt_ = 0.f; \
        _Pragma("unroll") for (int j = 0; j < 4; ++j) { \
            const float lv_ = (j == 0) ? lf_ : GA[I_][j - 1]; \
            const float rv_ = (j == 3) ? rt_ : GA[I_][j + 1]; \
            const float av_ = GA[I_ - 1][j]; \
            const float dv_ = ((I_) == 3) ? HA[0][j] : GA[I_ + 1][j]; \
            const float s4_ = (av_ + dv_) + (lv_ + rv_); \
            const float d_  = GA[I_][j] - GB[I_][j]; \
            const float e_  = fmaf(-4.0f, GA[I_][j], s4_); \
            float v_ = fmaf(ccv_[j], e_, GB[I_][j]); \
            v_ = fmaf(tcv_[j], d_, v_); \
            if (srcUp && gsu_r == (I_) && gsu_c == j) v_ += xbuf[TT]; \
            GB[I_][j] = v_; \
        } \
    } \
} while (0)

// dn-ghost row I_ (global row r0+4+I_, coef table row w4+8+I_); valid iff I_<=2-K_
#define GDN(GA, GB, HA, I_, K_, TT) do { \
    if ((I_) <= 2 - (K_)) { \
        const float4 tc4_ = *reinterpret_cast<const float4*>(&ldsTC[w4 + 8 + (I_)][y0]); \
        const float4 cc4_ = *reinterpret_cast<const float4*>(&ldsCC[w4 + 8 + (I_)][y0]); \
        const float tcv_[4] = {tc4_.x, tc4_.y, tc4_.z, tc4_.w}; \
        const float ccv_[4] = {cc4_.x, cc4_.y, cc4_.z, cc4_.w}; \
        float lf_ = __shfl_up(GA[I_][3], 1, 64); \
        float rt_ = __shfl_down(GA[I_][0], 1, 64); \
        if (l == 0)  lf_ = 0.f; \
        if (l == 63) rt_ = 0.f; \
        _Pragma("unroll") for (int j = 0; j < 4; ++j) { \
            const float lv_ = (j == 0) ? lf_ : GA[I_][j - 1]; \
            const float rv_ = (j == 3) ? rt_ : GA[I_][j + 1]; \
            const float av_ = ((I_) == 0) ? HA[3][j] : GA[I_ - 1][j]; \
            const float dv_ = GA[I_ + 1][j]; \
            const float s4_ = (av_ + dv_) + (lv_ + rv_); \
            const float d_  = GA[I_][j] - GB[I_][j]; \
            const float e_  = fmaf(-4.0f, GA[I_][j], s4_); \
            float v_ = fmaf(ccv_[j], e_, GB[I_][j]); \
            v_ = fmaf(tcv_[j], d_, v_); \
            if (srcDn && gsd_r == (I_) && gsd_c == j) v_ += xbuf[TT]; \
            GB[I_][j] = v_; \
        } \
    } \
} while (0)

// one substep inside a chunk: HA = h^{t}, HB = h^{t-1} -> h^{t+1} into HB
#define SUBK(HA, HB, GUA, GUB, GDA, GDB, K_, TT) do { \
    ROWC(HA, HB, 0, GUA[3], HA[1]); \
    ROWC(HA, HB, 1, HA[0],  HA[2]); \
    ROWC(HA, HB, 2, HA[1],  HA[3]); \
    ROWC(HA, HB, 3, HA[2],  GDA[0]); \
    SRCP(HB, 0, TT); SRCP(HB, 1, TT); SRCP(HB, 2, TT); SRCP(HB, 3, TT); \
    if (hasUp) { GUP(GUA, GUB, HA, 1, K_, TT); GUP(GUA, GUB, HA, 2, K_, TT); GUP(GUA, GUB, HA, 3, K_, TT); } \
    if (hasDn) { GDN(GDA, GDB, HA, 0, K_, TT); GDN(GDA, GDB, HA, 1, K_, TT); GDN(GDA, GDB, HA, 2, K_, TT); } \
} while (0)

__launch_bounds__(THREADS, 1)
__global__ void wave_multi(const float* __restrict__ xin,
                           const float* __restrict__ cin,
                           const float* __restrict__ bin,
                           const int* __restrict__ pxp,
                           const int* __restrict__ pyp,
                           const int* __restrict__ sxp,
                           const int* __restrict__ syp,
                           float* __restrict__ out)
{
    const int blk = blockIdx.x;
    const int b = blk >> 3;           // batch
    const int s = blk & 7;            // slab: rows [s*32, s*32+32)
    const int tid = threadIdx.x;
    const int w = tid >> 6;           // wave 0..7
    const int l = tid & 63;           // lane
    const int w4 = w << 2;
    const int r0 = s * 32 + w * 4;    // global row of tile row 0
    const int y0 = l * 4;             // global col of tile col 0

    // LDS: coef tables for slab-local rows -4..35 (table row = local+4),
    // single-buffered per-wave halo slot + chunk tag + read ack, x buffer.
    __shared__ float ldsTC[40][NY];            // 40 KB
    __shared__ float ldsCC[40][NY];            // 40 KB
    __shared__ float ldsHalo[WAVES][8][NY];    // 64 KB: [wave][0-3 h1, 4-7 h2]
    __shared__ int   ldsTag[WAVES];            // chunk id of slot content
    __shared__ int   ldsAck[WAVES];            // last chunk this wave consumed
    __shared__ float xbuf[T_];                 // 1 KB

    for (int e = tid; e < 40 * NY; e += THREADS) {
        const int row = e >> 8, col = e & 255;
        int grow = s * 32 - 4 + row;
        grow = grow < 0 ? 0 : (grow > 255 ? 255 : grow);   // clamped rows unused
        const float cv = cin[grow * NY + col];
        const float bv = bin[grow * NY + col];
        const float c1  = 1.0f / (1.0f + 0.25f * bv);      // 0.5*DT = 0.25
        const float csq = 0.25f * cv * cv;                 // DT^2 * c^2
        ldsTC[row][col] = 2.0f * c1;
        ldsCC[row][col] = c1 * csq;
    }
    for (int e = tid; e < WAVES * 8 * NY; e += THREADS)
        (&ldsHalo[0][0][0])[e] = 0.f;                      // chunk-0 state
    if (tid < WAVES) { ldsTag[tid] = 0; ldsAck[tid] = 0; } // tag0 valid; ack0 = consumed
    if (tid < T_) xbuf[tid] = xin[b * T_ + tid];
    __syncthreads();   // the only barrier

    // owned coefficients from the shared table (rows w4+4 .. w4+7)
    float TCr[4][4], CCr[4][4], h1[4][4], h2[4][4];
#pragma unroll
    for (int r = 0; r < 4; ++r) {
        const float4 t4 = *reinterpret_cast<const float4*>(&ldsTC[w4 + 4 + r][y0]);
        const float4 c4 = *reinterpret_cast<const float4*>(&ldsCC[w4 + 4 + r][y0]);
        TCr[r][0] = t4.x; TCr[r][1] = t4.y; TCr[r][2] = t4.z; TCr[r][3] = t4.w;
        CCr[r][0] = c4.x; CCr[r][1] = c4.y; CCr[r][2] = c4.z; CCr[r][3] = c4.w;
#pragma unroll
        for (int j = 0; j < 4; ++j) { h1[r][j] = 0.f; h2[r][j] = 0.f; }
    }

    // ghost state (both sides, both levels), zero at t=0
    float gu_a[4][4], gu_b[4][4], gd_a[4][4], gd_b[4][4];
#pragma unroll
    for (int i = 0; i < 4; ++i)
#pragma unroll
        for (int j = 0; j < 4; ++j) {
            gu_a[i][j] = 0.f; gu_b[i][j] = 0.f;
            gd_a[i][j] = 0.f; gd_b[i][j] = 0.f;
        }

    const bool hasUp = !(s == 0 && w == 0);
    const bool hasDn = !(s == NSLAB - 1 && w == WAVES - 1);

    const int sx = sxp[0], sy = syp[0];
    const bool srcHere = (sx >= r0 && sx < r0 + 4 && sy >= y0 && sy < y0 + 4);
    const int  src_r = sx - r0, src_c = sy - y0;
    const bool srcUp = hasUp && (sx >= r0 - 4 && sx < r0     && sy >= y0 && sy < y0 + 4);
    const int  gsu_r = sx - (r0 - 4), gsu_c = sy - y0;
    const bool srcDn = hasDn && (sx >= r0 + 4 && sx < r0 + 8 && sy >= y0 && sy < y0 + 4);
    const int  gsd_r = sx - (r0 + 4), gsd_c = sy - y0;
    bool pHere[NP];
    int  pr[NP], pc[NP];
#pragma unroll
    for (int q = 0; q < NP; ++q) {
        const int pxx = pxp[q], pyy = pyp[q];
        pHere[q] = (pxx >= r0 && pxx < r0 + 4 && pyy >= y0 && pyy < y0 + 4);
        pr[q] = pxx - r0;
        pc[q] = pyy - y0;
    }

#pragma unroll 1
    for (int c = 0; c < NCHUNK; ++c) {
        // ---- acquire ghost base (h^{4c}, h^{4c-1}); c=0 uses init zeros ----
        if (c > 0) {
            if (w > 0) {
                while (__hip_atomic_load(&ldsTag[w - 1], __ATOMIC_RELAXED,
                                         __HIP_MEMORY_SCOPE_WORKGROUP) != c) {}
                asm volatile("" ::: "memory");
#pragma unroll
                for (int i = 0; i < 4; ++i) {
                    const float4 a4 = *reinterpret_cast<const float4*>(&ldsHalo[w - 1][i][y0]);
                    const float4 b4 = *reinterpret_cast<const float4*>(&ldsHalo[w - 1][4 + i][y0]);
                    gu_a[i][0] = a4.x; gu_a[i][1] = a4.y; gu_a[i][2] = a4.z; gu_a[i][3] = a4.w;
                    gu_b[i][0] = b4.x; gu_b[i][1] = b4.y; gu_b[i][2] = b4.z; gu_b[i][3] = b4.w;
                }
            } else if (s > 0) {
                GPOLL32(gu_a, gu_b, 0, s - 1, c);
            }
            if (w < WAVES - 1) {
                while (__hip_atomic_load(&ldsTag[w + 1], __ATOMIC_RELAXED,
                                         __HIP_MEMORY_SCOPE_WORKGROUP) != c) {}
                asm volatile("" ::: "memory");
#pragma unroll
                for (int i = 0; i < 4; ++i) {
                    const float4 a4 = *reinterpret_cast<const float4*>(&ldsHalo[w + 1][i][y0]);
                    const float4 b4 = *reinterpret_cast<const float4*>(&ldsHalo[w + 1][4 + i][y0]);
                    gd_a[i][0] = a4.x; gd_a[i][1] = a4.y; gd_a[i][2] = a4.z; gd_a[i][3] = a4.w;
                    gd_b[i][0] = b4.x; gd_b[i][1] = b4.y; gd_b[i][2] = b4.z; gd_b[i][3] = b4.w;
                }
            } else if (s < NSLAB - 1) {
                GPOLL32(gd_a, gd_b, 1, s, c);
            }
            // signal "I consumed my neighbors' chunk-c slots" (DS in-order)
            asm volatile("s_waitcnt lgkmcnt(0)" ::: "memory");
            if (l == 0)
                __hip_atomic_store(&ldsAck[w], c, __ATOMIC_RELAXED,
                                   __HIP_MEMORY_SCOPE_WORKGROUP);
        }

        // ---- 4 substeps, pure register compute (no communication) ----
        const int t4 = 4 * c;
        SUBK(h1, h2, gu_a, gu_b, gd_a, gd_b, 0, t4 + 0);
        SUBK(h2, h1, gu_b, gu_a, gd_b, gd_a, 1, t4 + 1);
        SUBK(h1, h2, gu_a, gu_b, gd_a, gd_b, 2, t4 + 2);
        SUBK(h2, h1, gu_b, gu_a, gd_b, gd_a, 3, t4 + 3);
        // now h1 = h^{4c+4} (next base), h2 = h^{4c+3}

        // ---- publish next-chunk base rows ----
        if (c + 1 < NCHUNK) {
            // my slot's readers (w-1, w+1) must have consumed chunk-c data
            if (w > 0)
                while (__hip_atomic_load(&ldsAck[w - 1], __ATOMIC_RELAXED,
                                         __HIP_MEMORY_SCOPE_WORKGROUP) < c) {}
            if (w < WAVES - 1)
                while (__hip_atomic_load(&ldsAck[w + 1], __ATOMIC_RELAXED,
                                         __HIP_MEMORY_SCOPE_WORKGROUP) < c) {}
            asm volatile("" ::: "memory");
#pragma unroll
            for (int i = 0; i < 4; ++i) {
                *reinterpret_cast<float4*>(&ldsHalo[w][i][y0]) =
                    make_float4(h1[i][0], h1[i][1], h1[i][2], h1[i][3]);
                *reinterpret_cast<float4*>(&ldsHalo[w][4 + i][y0]) =
                    make_float4(h2[i][0], h2[i][1], h2[i][2], h2[i][3]);
            }
            asm volatile("s_waitcnt lgkmcnt(0)" ::: "memory");
            if (l == 0)
                __hip_atomic_store(&ldsTag[w], c + 1, __ATOMIC_RELAXED,
                                   __HIP_MEMORY_SCOPE_WORKGROUP);
            if (w == 0 && s > 0)                 GPUB32(1, s - 1, c + 1, h1, h2);
            if (w == WAVES - 1 && s < NSLAB - 1) GPUB32(0, s,     c + 1, h1, h2);
        }
    }
}

extern "C" void kernel_launch(void* const* d_in, const int* in_sizes, int n_in,
                              void* d_out, int out_size, void* d_ws, size_t ws_size,
                              hipStream_t stream)
{
    const float* x  = (const float*)d_in[0];
    const float* c  = (const float*)d_in[1];
    const float* bb = (const float*)d_in[2];
    const int*   px = (const int*)d_in[3];
    const int*   py = (const int*)d_in[4];
    const int*   sx = (const int*)d_in[5];
    const int*   sy = (const int*)d_in[6];
    float* out = (float*)d_out;

    const int words = B_ * NIF * 2 * 2 * 8 * NY;
    reset_halo<<<(words + 255) / 256, 256, 0, stream>>>();

    void* args[] = { (void*)&x, (void*)&c, (void*)&bb, (void*)&px, (void*)&py,
                     (void*)&sx, (void*)&sy, (void*)&out };
    hipLaunchCooperativeKernel(reinterpret_cast<void*>(wave_multi),
                               dim3(B_ * NSLAB), dim3(THREADS), args, 0, stream);
}

// Round 10
// 486.396 us; speedup vs baseline: 1.0127x; 1.0127x over previous
//
#include <hip/hip_runtime.h>

// WaveRNN: damped 2D wave equation, B=16, T=256, 256x256 grid, 3 probes.
// 16 slabs/batch x 16 batches = 256 WGs (cooperative, 1 per CU) x 256 thr
// (4 waves = 1 wave/SIMD -> compiler VGPR ceiling ~256, no 128 pin).
// Wave w owns rows s*16+4w..+3; lane l owns cols 4l..4l+3 (4x4 reg tile).
// FULLY CHUNKED K=4 temporal blocking, NO barriers in the main loop:
// every wave keeps 4 ghost rows on EACH side (both time levels) in registers
// and steps them redundantly (shrinking trapezoid). All synchronization is
// once per 4 steps:
//   intra-WG : single-buffered LDS halo slot per wave (8 rows) + chunk tag
//              (vals -> lgkmcnt(0) -> tag; in-order DS per wave => tag
//              visible implies vals visible) + read-ack so a producer never
//              overwrites an unread slot.
//   inter-WG : tagged 8-byte {chunk,value} packets, relaxed agent-scope
//              atomics, parity double-buffered (proven R3/R7/R8 protocol).
// Ghost + owner coefficients come from a 48 KB LDS table (24 rows x 256 for
// TC and CC) -> persistent regs ~128 + poll temps, fits the 256-VGPR budget.

#define B_    16
#define T_    256
#define NY    256
#define NP    3
#define NSLAB 16
#define WAVES 4
#define THREADS 256
#define NIF   (NSLAB - 1)
#define KCH   4
#define NCHUNK (T_ / KCH)

// [batch][iface][side][parity][rowfield 0..7][packed col = j*64 + lane]
// iface i joins slab i (upper) and slab i+1 (lower).
// side0 = slab i's bottom 4 rows; side1 = slab i+1's top 4 rows.
// rowfield 0..3 = h1 rows (level 4c), 4..7 = h2 rows (level 4c-1).
__device__ uint64_t g_halo[B_][NIF][2][2][8][NY];

__global__ void reset_halo()
{
    const int n = B_ * NIF * 2 * 2 * 8 * NY;
    int i = blockIdx.x * blockDim.x + threadIdx.x;
    if (i < n) (&g_halo[0][0][0][0][0][0])[i] = 0ull;   // tag0 = chunk-0 zeros
}

#define PACK(tag, f) (((uint64_t)(uint32_t)(tag) << 32) | (uint64_t)__float_as_uint(f))

#define GPOLL32(GA, GB, SIDE, IFACE, TAG) do { \
    uint64_t* gp_ = &g_halo[b][IFACE][SIDE][(TAG) & 1][0][0]; \
    uint64_t vv_[8][4]; bool ok_; \
    do { \
        ok_ = true; \
        _Pragma("unroll") for (int rf = 0; rf < 8; ++rf) \
            _Pragma("unroll") for (int j = 0; j < 4; ++j) \
                vv_[rf][j] = __hip_atomic_load(gp_ + rf * NY + j * 64 + l, \
                                               __ATOMIC_RELAXED, __HIP_MEMORY_SCOPE_AGENT); \
        _Pragma("unroll") for (int rf = 0; rf < 8; ++rf) \
            _Pragma("unroll") for (int j = 0; j < 4; ++j) \
                ok_ = ok_ && ((uint32_t)(vv_[rf][j] >> 32) == (uint32_t)(TAG)); \
    } while (!ok_); \
    _Pragma("unroll") for (int i = 0; i < 4; ++i) \
        _Pragma("unroll") for (int j = 0; j < 4; ++j) { \
            GA[i][j] = __uint_as_float((uint32_t)vv_[i][j]); \
            GB[i][j] = __uint_as_float((uint32_t)vv_[4 + i][j]); \
        } \
} while (0)

#define GPUB32(SIDE, IFACE, TAG1, HH1, HH2) do { \
    uint64_t* gp_ = &g_halo[b][IFACE][SIDE][(TAG1) & 1][0][0]; \
    _Pragma("unroll") for (int i = 0; i < 4; ++i) \
        _Pragma("unroll") for (int j = 0; j < 4; ++j) { \
            __hip_atomic_store(gp_ + i * NY + j * 64 + l, PACK(TAG1, HH1[i][j]), \
                               __ATOMIC_RELAXED, __HIP_MEMORY_SCOPE_AGENT); \
            __hip_atomic_store(gp_ + (4 + i) * NY + j * 64 + l, PACK(TAG1, HH2[i][j]), \
                               __ATOMIC_RELAXED, __HIP_MEMORY_SCOPE_AGENT); \
        } \
} while (0)

// hn = h2 + TC*(h1-h2) + CC*(s4 - 4*h1)   [c1*c2 == 2*c1 - 1]
#define ROWC(HA, HB, r, UPA, DNA) do { \
    float lf_ = __shfl_up(HA[r][3], 1, 64); \
    float rt_ = __shfl_down(HA[r][0], 1, 64); \
    if (l == 0)  lf_ = 0.f; \
    if (l == 63) rt_ = 0.f; \
    _Pragma("unroll") for (int j = 0; j < 4; ++j) { \
        const float lv_ = (j == 0) ? lf_ : HA[r][j - 1]; \
        const float rv_ = (j == 3) ? rt_ : HA[r][j + 1]; \
        const float s4_ = (UPA[j] + DNA[j]) + (lv_ + rv_); \
        const float d_  = HA[r][j] - HB[r][j]; \
        const float e_  = fmaf(-4.0f, HA[r][j], s4_); \
        float v_ = fmaf(CCr[r][j], e_, HB[r][j]); \
        v_ = fmaf(TCr[r][j], d_, v_); \
        HB[r][j] = v_; \
    } \
} while (0)

#define SRCP(HB, r, TT) do { \
    if (srcHere && src_r == (r)) { \
        _Pragma("unroll") for (int j = 0; j < 4; ++j) \
            if (src_c == j) HB[r][j] += xbuf[TT]; \
    } \
    _Pragma("unroll") for (int qq = 0; qq < NP; ++qq) { \
        if (pHere[qq] && pr[qq] == (r)) { \
            float v_ = 0.f; \
            _Pragma("unroll") for (int j = 0; j < 4; ++j) \
                if (pc[qq] == j) v_ = HB[r][j]; \
            out[((size_t)b * T_ + (TT)) * NP + qq] = v_; \
        } \
    } \
} while (0)

// up-ghost row I_ (global row r0-4+I_, coef table row w4+I_); valid iff I_>=K_+1
#define GUP(GA, GB, HA, I_, K_, TT) do { \
    if ((I_) >= (K_) + 1) { \
        const float4 tc4_ = *reinterpret_cast<const float4*>(&ldsTC[w4 + (I_)][y0]); \
        const float4 cc4_ = *reinterpret_cast<const float4*>(&ldsCC[w4 + (I_)][y0]); \
        const float tcv_[4] = {tc4_.x, tc4_.y, tc4_.z, tc4_.w}; \
        const float ccv_[4] = {cc4_.x, cc4_.y, cc4_.z, cc4_.w}; \
        float lf_ = __shfl_up(GA[I_][3], 1, 64); \
        float rt_ = __shfl_down(GA[I_][0], 1, 64); \
        if (l == 0)  lf_ = 0.f; \
        if (l == 63) rt_ = 0.f; \
        _Pragma("unroll") for (int j = 0; j < 4; ++j) { \
            const float lv_ = (j == 0) ? lf_ : GA[I_][j - 1]; \
            const float rv_ = (j == 3) ? rt_ : GA[I_][j + 1]; \
            const float av_ = GA[I_ - 1][j]; \
            const float dv_ = ((I_) == 3) ? HA[0][j] : GA[I_ + 1][j]; \
            const float s4_ = (av_ + dv_) + (lv_ + rv_); \
            const float d_  = GA[I_][j] - GB[I_][j]; \
            const float e_  = fmaf(-4.0f, GA[I_][j], s4_); \
            float v_ = fmaf(ccv_[j], e_, GB[I_][j]); \
            v_ = fmaf(tcv_[j], d_, v_); \
            if (srcUp && gsu_r == (I_) && gsu_c == j) v_ += xbuf[TT]; \
            GB[I_][j] = v_; \
        } \
    } \
} while (0)

// dn-ghost row I_ (global row r0+4+I_, coef table row w4+8+I_); valid iff I_<=2-K_
#define GDN(GA, GB, HA, I_, K_, TT) do { \
    if ((I_) <= 2 - (K_)) { \
        const float4 tc4_ = *reinterpret_cast<const float4*>(&ldsTC[w4 + 8 + (I_)][y0]); \
        const float4 cc4_ = *reinterpret_cast<const float4*>(&ldsCC[w4 + 8 + (I_)][y0]); \
        const float tcv_[4] = {tc4_.x, tc4_.y, tc4_.z, tc4_.w}; \
        const float ccv_[4] = {cc4_.x, cc4_.y, cc4_.z, cc4_.w}; \
        float lf_ = __shfl_up(GA[I_][3], 1, 64); \
        float rt_ = __shfl_down(GA[I_][0], 1, 64); \
        if (l == 0)  lf_ = 0.f; \
        if (l == 63) rt_ = 0.f; \
        _Pragma("unroll") for (int j = 0; j < 4; ++j) { \
            const float lv_ = (j == 0) ? lf_ : GA[I_][j - 1]; \
            const float rv_ = (j == 3) ? rt_ : GA[I_][j + 1]; \
            const float av_ = ((I_) == 0) ? HA[3][j] : GA[I_ - 1][j]; \
            const float dv_ = GA[I_ + 1][j]; \
            const float s4_ = (av_ + dv_) + (lv_ + rv_); \
            const float d_  = GA[I_][j] - GB[I_][j]; \
            const float e_  = fmaf(-4.0f, GA[I_][j], s4_); \
            float v_ = fmaf(ccv_[j], e_, GB[I_][j]); \
            v_ = fmaf(tcv_[j], d_, v_); \
            if (srcDn && gsd_r == (I_) && gsd_c == j) v_ += xbuf[TT]; \
            GB[I_][j] = v_; \
        } \
    } \
} while (0)

// one substep inside a chunk: HA = h^{t}, HB = h^{t-1} -> h^{t+1} into HB
#define SUBK(HA, HB, GUA, GUB, GDA, GDB, K_, TT) do { \
    ROWC(HA, HB, 0, GUA[3], HA[1]); \
    ROWC(HA, HB, 1, HA[0],  HA[2]); \
    ROWC(HA, HB, 2, HA[1],  HA[3]); \
    ROWC(HA, HB, 3, HA[2],  GDA[0]); \
    SRCP(HB, 0, TT); SRCP(HB, 1, TT); SRCP(HB, 2, TT); SRCP(HB, 3, TT); \
    if (hasUp) { GUP(GUA, GUB, HA, 1, K_, TT); GUP(GUA, GUB, HA, 2, K_, TT); GUP(GUA, GUB, HA, 3, K_, TT); } \
    if (hasDn) { GDN(GDA, GDB, HA, 0, K_, TT); GDN(GDA, GDB, HA, 1, K_, TT); GDN(GDA, GDB, HA, 2, K_, TT); } \
} while (0)

__launch_bounds__(THREADS, 1)
__global__ void wave_multi(const float* __restrict__ xin,
                           const float* __restrict__ cin,
                           const float* __restrict__ bin,
                           const int* __restrict__ pxp,
                           const int* __restrict__ pyp,
                           const int* __restrict__ sxp,
                           const int* __restrict__ syp,
                           float* __restrict__ out)
{
    const int blk = blockIdx.x;
    const int b = blk >> 4;           // batch
    const int s = blk & 15;           // slab: rows [s*16, s*16+16)
    const int tid = threadIdx.x;
    const int w = tid >> 6;           // wave 0..3
    const int l = tid & 63;           // lane
    const int w4 = w << 2;
    const int r0 = s * 16 + w * 4;    // global row of tile row 0
    const int y0 = l * 4;             // global col of tile col 0

    // LDS: coef tables for slab-local rows -4..19 (table row = local+4),
    // single-buffered per-wave halo slot + chunk tag + read ack, x buffer.
    __shared__ float ldsTC[24][NY];            // 24 KB
    __shared__ float ldsCC[24][NY];            // 24 KB
    __shared__ float ldsHalo[WAVES][8][NY];    // 32 KB: [wave][0-3 h1, 4-7 h2]
    __shared__ int   ldsTag[WAVES];            // chunk id of slot content
    __shared__ int   ldsAck[WAVES];            // last chunk this wave consumed
    __shared__ float xbuf[T_];                 // 1 KB

    for (int e = tid; e < 24 * NY; e += THREADS) {
        const int row = e >> 8, col = e & 255;
        int grow = s * 16 - 4 + row;
        grow = grow < 0 ? 0 : (grow > 255 ? 255 : grow);   // clamped rows unused
        const float cv = cin[grow * NY + col];
        const float bv = bin[grow * NY + col];
        const float c1  = 1.0f / (1.0f + 0.25f * bv);      // 0.5*DT = 0.25
        const float csq = 0.25f * cv * cv;                 // DT^2 * c^2
        ldsTC[row][col] = 2.0f * c1;
        ldsCC[row][col] = c1 * csq;
    }
    for (int e = tid; e < WAVES * 8 * NY; e += THREADS)
        (&ldsHalo[0][0][0])[e] = 0.f;                      // chunk-0 state
    if (tid < WAVES) { ldsTag[tid] = 0; ldsAck[tid] = 0; } // tag0 valid; ack0 consumed
    if (tid < T_) xbuf[tid] = xin[b * T_ + tid];
    __syncthreads();   // the only barrier

    // owned coefficients from the shared table (rows w4+4 .. w4+7)
    float TCr[4][4], CCr[4][4], h1[4][4], h2[4][4];
#pragma unroll
    for (int r = 0; r < 4; ++r) {
        const float4 t4 = *reinterpret_cast<const float4*>(&ldsTC[w4 + 4 + r][y0]);
        const float4 c4 = *reinterpret_cast<const float4*>(&ldsCC[w4 + 4 + r][y0]);
        TCr[r][0] = t4.x; TCr[r][1] = t4.y; TCr[r][2] = t4.z; TCr[r][3] = t4.w;
        CCr[r][0] = c4.x; CCr[r][1] = c4.y; CCr[r][2] = c4.z; CCr[r][3] = c4.w;
#pragma unroll
        for (int j = 0; j < 4; ++j) { h1[r][j] = 0.f; h2[r][j] = 0.f; }
    }

    // ghost state (both sides, both levels), zero at t=0
    float gu_a[4][4], gu_b[4][4], gd_a[4][4], gd_b[4][4];
#pragma unroll
    for (int i = 0; i < 4; ++i)
#pragma unroll
        for (int j = 0; j < 4; ++j) {
            gu_a[i][j] = 0.f; gu_b[i][j] = 0.f;
            gd_a[i][j] = 0.f; gd_b[i][j] = 0.f;
        }

    const bool hasUp = !(s == 0 && w == 0);
    const bool hasDn = !(s == NSLAB - 1 && w == WAVES - 1);

    const int sx = sxp[0], sy = syp[0];
    const bool srcHere = (sx >= r0 && sx < r0 + 4 && sy >= y0 && sy < y0 + 4);
    const int  src_r = sx - r0, src_c = sy - y0;
    const bool srcUp = hasUp && (sx >= r0 - 4 && sx < r0     && sy >= y0 && sy < y0 + 4);
    const int  gsu_r = sx - (r0 - 4), gsu_c = sy - y0;
    const bool srcDn = hasDn && (sx >= r0 + 4 && sx < r0 + 8 && sy >= y0 && sy < y0 + 4);
    const int  gsd_r = sx - (r0 + 4), gsd_c = sy - y0;
    bool pHere[NP];
    int  pr[NP], pc[NP];
#pragma unroll
    for (int q = 0; q < NP; ++q) {
        const int pxx = pxp[q], pyy = pyp[q];
        pHere[q] = (pxx >= r0 && pxx < r0 + 4 && pyy >= y0 && pyy < y0 + 4);
        pr[q] = pxx - r0;
        pc[q] = pyy - y0;
    }

#pragma unroll 1
    for (int c = 0; c < NCHUNK; ++c) {
        // ---- acquire ghost base (h^{4c}, h^{4c-1}); c=0 uses init zeros ----
        if (c > 0) {
            if (w > 0) {
                while (__hip_atomic_load(&ldsTag[w - 1], __ATOMIC_RELAXED,
                                         __HIP_MEMORY_SCOPE_WORKGROUP) != c) {}
                asm volatile("" ::: "memory");
#pragma unroll
                for (int i = 0; i < 4; ++i) {
                    const float4 a4 = *reinterpret_cast<const float4*>(&ldsHalo[w - 1][i][y0]);
                    const float4 b4 = *reinterpret_cast<const float4*>(&ldsHalo[w - 1][4 + i][y0]);
                    gu_a[i][0] = a4.x; gu_a[i][1] = a4.y; gu_a[i][2] = a4.z; gu_a[i][3] = a4.w;
                    gu_b[i][0] = b4.x; gu_b[i][1] = b4.y; gu_b[i][2] = b4.z; gu_b[i][3] = b4.w;
                }
            } else if (s > 0) {
                GPOLL32(gu_a, gu_b, 0, s - 1, c);
            }
            if (w < WAVES - 1) {
                while (__hip_atomic_load(&ldsTag[w + 1], __ATOMIC_RELAXED,
                                         __HIP_MEMORY_SCOPE_WORKGROUP) != c) {}
                asm volatile("" ::: "memory");
#pragma unroll
                for (int i = 0; i < 4; ++i) {
                    const float4 a4 = *reinterpret_cast<const float4*>(&ldsHalo[w + 1][i][y0]);
                    const float4 b4 = *reinterpret_cast<const float4*>(&ldsHalo[w + 1][4 + i][y0]);
                    gd_a[i][0] = a4.x; gd_a[i][1] = a4.y; gd_a[i][2] = a4.z; gd_a[i][3] = a4.w;
                    gd_b[i][0] = b4.x; gd_b[i][1] = b4.y; gd_b[i][2] = b4.z; gd_b[i][3] = b4.w;
                }
            } else if (s < NSLAB - 1) {
                GPOLL32(gd_a, gd_b, 1, s, c);
            }
            // signal "I consumed my neighbors' chunk-c slots" (DS in-order)
            asm volatile("s_waitcnt lgkmcnt(0)" ::: "memory");
            if (l == 0)
                __hip_atomic_store(&ldsAck[w], c, __ATOMIC_RELAXED,
                                   __HIP_MEMORY_SCOPE_WORKGROUP);
        }

        // ---- 4 substeps, pure register compute (no communication) ----
        const int t4 = 4 * c;
        SUBK(h1, h2, gu_a, gu_b, gd_a, gd_b, 0, t4 + 0);
        SUBK(h2, h1, gu_b, gu_a, gd_b, gd_a, 1, t4 + 1);
        SUBK(h1, h2, gu_a, gu_b, gd_a, gd_b, 2, t4 + 2);
        SUBK(h2, h1, gu_b, gu_a, gd_b, gd_a, 3, t4 + 3);
        // now h1 = h^{4c+4} (next base), h2 = h^{4c+3}

        // ---- publish next-chunk base rows ----
        if (c + 1 < NCHUNK) {
            // my slot's readers (w-1, w+1) must have consumed chunk-c data
            if (w > 0)
                while (__hip_atomic_load(&ldsAck[w - 1], __ATOMIC_RELAXED,
                                         __HIP_MEMORY_SCOPE_WORKGROUP) < c) {}
            if (w < WAVES - 1)
                while (__hip_atomic_load(&ldsAck[w + 1], __ATOMIC_RELAXED,
                                         __HIP_MEMORY_SCOPE_WORKGROUP) < c) {}
            asm volatile("" ::: "memory");
#pragma unroll
            for (int i = 0; i < 4; ++i) {
                *reinterpret_cast<float4*>(&ldsHalo[w][i][y0]) =
                    make_float4(h1[i][0], h1[i][1], h1[i][2], h1[i][3]);
                *reinterpret_cast<float4*>(&ldsHalo[w][4 + i][y0]) =
                    make_float4(h2[i][0], h2[i][1], h2[i][2], h2[i][3]);
            }
            asm volatile("s_waitcnt lgkmcnt(0)" ::: "memory");
            if (l == 0)
                __hip_atomic_store(&ldsTag[w], c + 1, __ATOMIC_RELAXED,
                                   __HIP_MEMORY_SCOPE_WORKGROUP);
            if (w == 0 && s > 0)                 GPUB32(1, s - 1, c + 1, h1, h2);
            if (w == WAVES - 1 && s < NSLAB - 1) GPUB32(0, s,     c + 1, h1, h2);
        }
    }
}

extern "C" void kernel_launch(void* const* d_in, const int* in_sizes, int n_in,
                              void* d_out, int out_size, void* d_ws, size_t ws_size,
                              hipStream_t stream)
{
    const float* x  = (const float*)d_in[0];
    const float* c  = (const float*)d_in[1];
    const float* bb = (const float*)d_in[2];
    const int*   px = (const int*)d_in[3];
    const int*   py = (const int*)d_in[4];
    const int*   sx = (const int*)d_in[5];
    const int*   sy = (const int*)d_in[6];
    float* out = (float*)d_out;

    const int words = B_ * NIF * 2 * 2 * 8 * NY;
    reset_halo<<<(words + 255) / 256, 256, 0, stream>>>();

    void* args[] = { (void*)&x, (void*)&c, (void*)&bb, (void*)&px, (void*)&py,
                     (void*)&sx, (void*)&sy, (void*)&out };
    hipLaunchCooperativeKernel(reinterpret_cast<void*>(wave_multi),
                               dim3(B_ * NSLAB), dim3(THREADS), args, 0, stream);
}

// Round 11
// 448.465 us; speedup vs baseline: 1.0984x; 1.0846x over previous
//
#include <hip/hip_runtime.h>

// WaveRNN: damped 2D wave equation, B=16, T=256, 256x256 grid, 3 probes.
// 8 slabs/batch (128 WGs x 512 thr, cooperative). Wave w owns rows s*32+4w..+3,
// lane l owns cols 4l..4l+3 (4x4 register tile).
// Structure = R4 barrier-free skeleton + K=4 seam chunking (R7) + three fixes:
//   1. s_sleep in ALL spin loops (LDS tag + global poll) -> spinning waves
//      stop hammering the LDS/VMEM pipes that computing waves need.
//   2. Ring-depth-4 LDS halos (tag = t, slot = t&3) -> inter-wave skew
//      tolerance of 3 steps; seam-stall jitter is absorbed, not convoyed.
//      (Overwrite safety: I write slot for t+1 over t-3; my computing t+1
//      implies neighbor published t, implies it consumed my t-1, and per-wave
//      consumption is in step order, so my t-3 was consumed. No acks needed.)
//   3. Interior rows (1,2) computed BEFORE neighbor acquire each substep.
// Seam waves (w==0,s>0 / w==7,s<7) keep 4 ghost rows (both levels) in regs,
// step them with the shrinking trapezoid, and exchange tagged 8-byte
// {chunk,value} packets once per 4 steps (relaxed agent-scope atomics,
// parity double-buffered). Ghost coefs from an 8 KB LDS table; ghost math is
// bitwise-identical to the owner's.

#define B_    16
#define T_    256
#define NY    256
#define NP    3
#define NSLAB 8
#define WAVES 8
#define THREADS 512
#define NIF   (NSLAB - 1)
#define KCH   4
#define NCHUNK (T_ / KCH)

// [batch][iface][side][parity][rowfield 0..7][packed col = j*64 + lane]
// side0 = slab i's bottom 4 rows; side1 = slab i+1's top 4 rows.
// rowfield 0..3 = h1 rows (level 4c), 4..7 = h2 rows (level 4c-1).
__device__ uint64_t g_halo[B_][NIF][2][2][8][NY];

__global__ void reset_halo()
{
    const int n = B_ * NIF * 2 * 2 * 8 * NY;
    int i = blockIdx.x * blockDim.x + threadIdx.x;
    if (i < n) (&g_halo[0][0][0][0][0][0])[i] = 0ull;   // tag0 = chunk-0 zeros
}

#define PACK(tag, f) (((uint64_t)(uint32_t)(tag) << 32) | (uint64_t)__float_as_uint(f))

#define GPOLL32(GA, GB, SIDE, IFACE, TAG) do { \
    uint64_t* gp_ = &g_halo[b][IFACE][SIDE][(TAG) & 1][0][0]; \
    uint64_t vv_[8][4]; bool ok_; bool first_ = true; \
    do { \
        if (!first_) __builtin_amdgcn_s_sleep(2); \
        first_ = false; \
        ok_ = true; \
        _Pragma("unroll") for (int rf = 0; rf < 8; ++rf) \
            _Pragma("unroll") for (int j = 0; j < 4; ++j) \
                vv_[rf][j] = __hip_atomic_load(gp_ + rf * NY + j * 64 + l, \
                                               __ATOMIC_RELAXED, __HIP_MEMORY_SCOPE_AGENT); \
        _Pragma("unroll") for (int rf = 0; rf < 8; ++rf) \
            _Pragma("unroll") for (int j = 0; j < 4; ++j) \
                ok_ = ok_ && ((uint32_t)(vv_[rf][j] >> 32) == (uint32_t)(TAG)); \
    } while (!ok_); \
    _Pragma("unroll") for (int i = 0; i < 4; ++i) \
        _Pragma("unroll") for (int j = 0; j < 4; ++j) { \
            GA[i][j] = __uint_as_float((uint32_t)vv_[i][j]); \
            GB[i][j] = __uint_as_float((uint32_t)vv_[4 + i][j]); \
        } \
} while (0)

#define GPUB32(SIDE, IFACE, TAG1, HH1, HH2) do { \
    uint64_t* gp_ = &g_halo[b][IFACE][SIDE][(TAG1) & 1][0][0]; \
    _Pragma("unroll") for (int i = 0; i < 4; ++i) \
        _Pragma("unroll") for (int j = 0; j < 4; ++j) { \
            __hip_atomic_store(gp_ + i * NY + j * 64 + l, PACK(TAG1, HH1[i][j]), \
                               __ATOMIC_RELAXED, __HIP_MEMORY_SCOPE_AGENT); \
            __hip_atomic_store(gp_ + (4 + i) * NY + j * 64 + l, PACK(TAG1, HH2[i][j]), \
                               __ATOMIC_RELAXED, __HIP_MEMORY_SCOPE_AGENT); \
        } \
} while (0)

// hn = h2 + TC*(h1-h2) + CC*(s4 - 4*h1)   [c1*c2 == 2*c1 - 1]
#define ROWC(HA, HB, r, UPA, DNA) do { \
    float lf_ = __shfl_up(HA[r][3], 1, 64); \
    float rt_ = __shfl_down(HA[r][0], 1, 64); \
    if (l == 0)  lf_ = 0.f; \
    if (l == 63) rt_ = 0.f; \
    _Pragma("unroll") for (int j = 0; j < 4; ++j) { \
        const float lv_ = (j == 0) ? lf_ : HA[r][j - 1]; \
        const float rv_ = (j == 3) ? rt_ : HA[r][j + 1]; \
        const float s4_ = (UPA[j] + DNA[j]) + (lv_ + rv_); \
        const float d_  = HA[r][j] - HB[r][j]; \
        const float e_  = fmaf(-4.0f, HA[r][j], s4_); \
        float v_ = fmaf(CCr[r][j], e_, HB[r][j]); \
        v_ = fmaf(TCr[r][j], d_, v_); \
        HB[r][j] = v_; \
    } \
} while (0)

#define SRCP(HB, r, TT) do { \
    if (srcHere && src_r == (r)) { \
        _Pragma("unroll") for (int j = 0; j < 4; ++j) \
            if (src_c == j) HB[r][j] += xbuf[TT]; \
    } \
    _Pragma("unroll") for (int qq = 0; qq < NP; ++qq) { \
        if (pHere[qq] && pr[qq] == (r)) { \
            float v_ = 0.f; \
            _Pragma("unroll") for (int j = 0; j < 4; ++j) \
                if (pc[qq] == j) v_ = HB[r][j]; \
            out[((size_t)b * T_ + (TT)) * NP + qq] = v_; \
        } \
    } \
} while (0)

// up-ghost row I_ (global row r0-4+I_, coef row I_); valid update iff I_>=K_+1
#define GUP(GA, GB, HA, I_, K_, TT) do { \
    if ((I_) >= (K_) + 1) { \
        const float4 tc4_ = *reinterpret_cast<const float4*>(&ldsGTC[I_][y0]); \
        const float4 cc4_ = *reinterpret_cast<const float4*>(&ldsGCC[I_][y0]); \
        const float tcv_[4] = {tc4_.x, tc4_.y, tc4_.z, tc4_.w}; \
        const float ccv_[4] = {cc4_.x, cc4_.y, cc4_.z, cc4_.w}; \
        float lf_ = __shfl_up(GA[I_][3], 1, 64); \
        float rt_ = __shfl_down(GA[I_][0], 1, 64); \
        if (l == 0)  lf_ = 0.f; \
        if (l == 63) rt_ = 0.f; \
        _Pragma("unroll") for (int j = 0; j < 4; ++j) { \
            const float lv_ = (j == 0) ? lf_ : GA[I_][j - 1]; \
            const float rv_ = (j == 3) ? rt_ : GA[I_][j + 1]; \
            const float av_ = GA[I_ - 1][j]; \
            const float dv_ = ((I_) == 3) ? HA[0][j] : GA[I_ + 1][j]; \
            const float s4_ = (av_ + dv_) + (lv_ + rv_); \
            const float d_  = GA[I_][j] - GB[I_][j]; \
            const float e_  = fmaf(-4.0f, GA[I_][j], s4_); \
            float v_ = fmaf(ccv_[j], e_, GB[I_][j]); \
            v_ = fmaf(tcv_[j], d_, v_); \
            if (srcUp && gsu_r == (I_) && gsu_c == j) v_ += xbuf[TT]; \
            GB[I_][j] = v_; \
        } \
    } \
} while (0)

// dn-ghost row I_ (global row r0+4+I_, coef row 4+I_); valid update iff I_<=2-K_
#define GDN(GA, GB, HA, I_, K_, TT) do { \
    if ((I_) <= 2 - (K_)) { \
        const float4 tc4_ = *reinterpret_cast<const float4*>(&ldsGTC[4 + (I_)][y0]); \
        const float4 cc4_ = *reinterpret_cast<const float4*>(&ldsGCC[4 + (I_)][y0]); \
        const float tcv_[4] = {tc4_.x, tc4_.y, tc4_.z, tc4_.w}; \
        const float ccv_[4] = {cc4_.x, cc4_.y, cc4_.z, cc4_.w}; \
        float lf_ = __shfl_up(GA[I_][3], 1, 64); \
        float rt_ = __shfl_down(GA[I_][0], 1, 64); \
        if (l == 0)  lf_ = 0.f; \
        if (l == 63) rt_ = 0.f; \
        _Pragma("unroll") for (int j = 0; j < 4; ++j) { \
            const float lv_ = (j == 0) ? lf_ : GA[I_][j - 1]; \
            const float rv_ = (j == 3) ? rt_ : GA[I_][j + 1]; \
            const float av_ = ((I_) == 0) ? HA[3][j] : GA[I_ - 1][j]; \
            const float dv_ = GA[I_ + 1][j]; \
            const float s4_ = (av_ + dv_) + (lv_ + rv_); \
            const float d_  = GA[I_][j] - GB[I_][j]; \
            const float e_  = fmaf(-4.0f, GA[I_][j], s4_); \
            float v_ = fmaf(ccv_[j], e_, GB[I_][j]); \
            v_ = fmaf(tcv_[j], d_, v_); \
            if (srcDn && gsd_r == (I_) && gsd_c == j) v_ += xbuf[TT]; \
            GB[I_][j] = v_; \
        } \
    } \
} while (0)

// One substep: H1=h^t, H2=h^{t-1} -> h^{t+1} into H2. K_ = substep in chunk.
// Order: interior rows (no deps) -> acquire neighbors -> boundary rows ->
// publish (slot (t+1)&3) -> ghost trapezoid -> interior src/probes.
#define SUB(H1, H2, GA, GB, K_, TT) do { \
    const int P_ = (TT) & 3; \
    const int Q_ = ((TT) + 1) & 3; \
    ROWC(H1, H2, 1, H1[0], H1[2]); \
    ROWC(H1, H2, 2, H1[1], H1[3]); \
    float gu_[4], gd_[4]; \
    if (w == 0) { \
        if (s == 0) { gu_[0] = gu_[1] = gu_[2] = gu_[3] = 0.f; } \
        else { gu_[0] = GA[3][0]; gu_[1] = GA[3][1]; gu_[2] = GA[3][2]; gu_[3] = GA[3][3]; } \
    } else { \
        while (__hip_atomic_load(&r3t[w - 1][P_], __ATOMIC_RELAXED, __HIP_MEMORY_SCOPE_WORKGROUP) != (TT)) \
            __builtin_amdgcn_s_sleep(1); \
        asm volatile("" ::: "memory"); \
        const float4 u4_ = *reinterpret_cast<const float4*>(&r3v[w - 1][P_][y0]); \
        gu_[0] = u4_.x; gu_[1] = u4_.y; gu_[2] = u4_.z; gu_[3] = u4_.w; \
    } \
    if (w == WAVES - 1) { \
        if (s == NSLAB - 1) { gd_[0] = gd_[1] = gd_[2] = gd_[3] = 0.f; } \
        else { gd_[0] = GA[0][0]; gd_[1] = GA[0][1]; gd_[2] = GA[0][2]; gd_[3] = GA[0][3]; } \
    } else { \
        while (__hip_atomic_load(&r0t[w + 1][P_], __ATOMIC_RELAXED, __HIP_MEMORY_SCOPE_WORKGROUP) != (TT)) \
            __builtin_amdgcn_s_sleep(1); \
        asm volatile("" ::: "memory"); \
        const float4 d4_ = *reinterpret_cast<const float4*>(&r0v[w + 1][P_][y0]); \
        gd_[0] = d4_.x; gd_[1] = d4_.y; gd_[2] = d4_.z; gd_[3] = d4_.w; \
    } \
    ROWC(H1, H2, 0, gu_, H1[1]); \
    ROWC(H1, H2, 3, H1[2], gd_); \
    SRCP(H2, 0, TT); \
    SRCP(H2, 3, TT); \
    if (w > 0) \
        *reinterpret_cast<float4*>(&r0v[w][Q_][y0]) = make_float4(H2[0][0], H2[0][1], H2[0][2], H2[0][3]); \
    if (w < WAVES - 1) \
        *reinterpret_cast<float4*>(&r3v[w][Q_][y0]) = make_float4(H2[3][0], H2[3][1], H2[3][2], H2[3][3]); \
    asm volatile("s_waitcnt lgkmcnt(0)" ::: "memory"); \
    if (l == 0) { \
        if (w > 0) \
            __hip_atomic_store(&r0t[w][Q_], (TT) + 1, __ATOMIC_RELAXED, __HIP_MEMORY_SCOPE_WORKGROUP); \
        if (w < WAVES - 1) \
            __hip_atomic_store(&r3t[w][Q_], (TT) + 1, __ATOMIC_RELAXED, __HIP_MEMORY_SCOPE_WORKGROUP); \
    } \
    if (upG) { GUP(GA, GB, H1, 1, K_, TT); GUP(GA, GB, H1, 2, K_, TT); GUP(GA, GB, H1, 3, K_, TT); } \
    if (dnG) { GDN(GA, GB, H1, 0, K_, TT); GDN(GA, GB, H1, 1, K_, TT); GDN(GA, GB, H1, 2, K_, TT); } \
    SRCP(H2, 1, TT); \
    SRCP(H2, 2, TT); \
} while (0)

__launch_bounds__(THREADS, 1)
__global__ void wave_multi(const float* __restrict__ xin,
                           const float* __restrict__ cin,
                           const float* __restrict__ bin,
                           const int* __restrict__ pxp,
                           const int* __restrict__ pyp,
                           const int* __restrict__ sxp,
                           const int* __restrict__ syp,
                           float* __restrict__ out)
{
    const int blk = blockIdx.x;
    const int b = blk >> 3;           // batch
    const int s = blk & 7;            // slab: rows [s*32, s*32+32)
    const int tid = threadIdx.x;
    const int w = tid >> 6;           // wave 0..7
    const int l = tid & 63;           // lane
    const int r0 = s * 32 + w * 4;    // global row of tile row 0
    const int y0 = l * 4;             // global col of tile col 0

    __shared__ float xbuf[T_];
    __shared__ float r0v[WAVES][4][NY];   // wave w's row0, ring slot = t&3
    __shared__ float r3v[WAVES][4][NY];   // wave w's row3, ring slot = t&3
    __shared__ int   r0t[WAVES][4];       // tag = t of slot content
    __shared__ int   r3t[WAVES][4];
    __shared__ float ldsGTC[8][NY];       // ghost coefs: 0-3 up (r0s-4..-1), 4-7 dn (r0s+32..+35)
    __shared__ float ldsGCC[8][NY];

    for (int i = tid; i < WAVES * 4 * NY; i += THREADS) {
        (&r0v[0][0][0])[i] = 0.f;
        (&r3v[0][0][0])[i] = 0.f;
    }
    if (tid < WAVES * 4) {
        const int w_ = tid >> 2, p_ = tid & 3;
        r0t[w_][p_] = (p_ == 0) ? 0 : -1;   // slot0 holds valid step-0 zeros
        r3t[w_][p_] = (p_ == 0) ? 0 : -1;
    }
    if (tid < T_) xbuf[tid] = xin[b * T_ + tid];
    // ghost coef table (clamped at grid edges, unused there)
    for (int e = tid; e < 8 * NY; e += THREADS) {
        const int row = e >> 8, col = e & 255;
        int grow = (row < 4) ? (s * 32 - 4 + row) : (s * 32 + 32 + (row - 4));
        grow = grow < 0 ? 0 : (grow > 255 ? 255 : grow);
        const float cv = cin[grow * NY + col];
        const float bv = bin[grow * NY + col];
        const float c1  = 1.0f / (1.0f + 0.25f * bv);
        const float csq = 0.25f * cv * cv;
        ldsGTC[row][col] = 2.0f * c1;
        ldsGCC[row][col] = c1 * csq;
    }

    // owned state + compressed coefficients: TC = 2*c1, CC = c1*(DT^2*c^2)
    float h1[4][4], h2[4][4], TCr[4][4], CCr[4][4];
#pragma unroll
    for (int r = 0; r < 4; ++r) {
        const float4 cv = *reinterpret_cast<const float4*>(&cin[(r0 + r) * NY + y0]);
        const float4 bv = *reinterpret_cast<const float4*>(&bin[(r0 + r) * NY + y0]);
        const float cvv[4] = {cv.x, cv.y, cv.z, cv.w};
        const float bvv[4] = {bv.x, bv.y, bv.z, bv.w};
#pragma unroll
        for (int j = 0; j < 4; ++j) {
            const float c1  = 1.0f / (1.0f + 0.25f * bvv[j]);
            const float csq = 0.25f * cvv[j] * cvv[j];
            TCr[r][j] = 2.0f * c1;
            CCr[r][j] = c1 * csq;
            h1[r][j] = 0.f;
            h2[r][j] = 0.f;
        }
    }

    // register ghosts for slab-boundary waves (both time levels), zero at t=0
    const bool upG = (w == 0 && s > 0);
    const bool dnG = (w == WAVES - 1 && s < NSLAB - 1);
    float ga[4][4], gb[4][4];
#pragma unroll
    for (int i = 0; i < 4; ++i)
#pragma unroll
        for (int j = 0; j < 4; ++j) { ga[i][j] = 0.f; gb[i][j] = 0.f; }

    const int sx = sxp[0], sy = syp[0];
    const bool srcHere = (sx >= r0 && sx < r0 + 4 && sy >= y0 && sy < y0 + 4);
    const int  src_r = sx - r0, src_c = sy - y0;
    const bool srcUp = upG && (sx >= r0 - 4 && sx < r0     && sy >= y0 && sy < y0 + 4);
    const int  gsu_r = sx - (r0 - 4), gsu_c = sy - y0;
    const bool srcDn = dnG && (sx >= r0 + 4 && sx < r0 + 8 && sy >= y0 && sy < y0 + 4);
    const int  gsd_r = sx - (r0 + 4), gsd_c = sy - y0;
    bool pHere[NP];
    int  pr[NP], pc[NP];
#pragma unroll
    for (int q = 0; q < NP; ++q) {
        const int pxx = pxp[q], pyy = pyp[q];
        pHere[q] = (pxx >= r0 && pxx < r0 + 4 && pyy >= y0 && pyy < y0 + 4);
        pr[q] = pxx - r0;
        pc[q] = pyy - y0;
    }

    __syncthreads();   // the only barrier: LDS init

#pragma unroll 1
    for (int c = 0; c < NCHUNK; ++c) {
        // acquire neighbor base rows for this chunk: ga=h^{4c}, gb=h^{4c-1}
        if (c > 0) {
            if (upG) GPOLL32(ga, gb, 0, s - 1, c);
            if (dnG) GPOLL32(ga, gb, 1, s, c);
        }

        const int t4 = 4 * c;
        SUB(h1, h2, ga, gb, 0, t4 + 0);
        SUB(h2, h1, gb, ga, 1, t4 + 1);
        SUB(h1, h2, ga, gb, 2, t4 + 2);
        SUB(h2, h1, gb, ga, 3, t4 + 3);
        // now h1 = h^{4c+4}, h2 = h^{4c+3}

        // publish own boundary rows (both levels) for neighbors' next chunk
        if (c + 1 < NCHUNK) {
            if (upG) GPUB32(1, s - 1, c + 1, h1, h2);
            if (dnG) GPUB32(0, s,     c + 1, h1, h2);
        }
    }
}

extern "C" void kernel_launch(void* const* d_in, const int* in_sizes, int n_in,
                              void* d_out, int out_size, void* d_ws, size_t ws_size,
                              hipStream_t stream)
{
    const float* x  = (const float*)d_in[0];
    const float* c  = (const float*)d_in[1];
    const float* bb = (const float*)d_in[2];
    const int*   px = (const int*)d_in[3];
    const int*   py = (const int*)d_in[4];
    const int*   sx = (const int*)d_in[5];
    const int*   sy = (const int*)d_in[6];
    float* out = (float*)d_out;

    const int words = B_ * NIF * 2 * 2 * 8 * NY;
    reset_halo<<<(words + 255) / 256, 256, 0, stream>>>();

    void* args[] = { (void*)&x, (void*)&c, (void*)&bb, (void*)&px, (void*)&py,
                     (void*)&sx, (void*)&sy, (void*)&out };
    hipLaunchCooperativeKernel(reinterpret_cast<void*>(wave_multi),
                               dim3(B_ * NSLAB), dim3(THREADS), args, 0, stream);
}

// Round 12
// 355.713 us; speedup vs baseline: 1.3848x; 1.2607x over previous
//
#include <hip/hip_runtime.h>

// WaveRNN: damped 2D wave equation, B=16, T=256, 256x256 grid, 3 probes.
// Structure = R4 champion, byte-identical except two deltas:
//   1. XCD colocation: blockIdx round-robins over 8 XCDs (blk%8 = XCD), so
//      map blk -> (b,s) with b%8 == blk%8: ALL 8 slabs of a batch share one
//      XCD (2 batches x 8 slabs = 16 WGs per XCD). Seam publish->poll hops
//      become same-XCD instead of worst-case cross-XCD.
//   2. s_sleep(1) backoff in the GLOBAL seam poll loops only (LDS spins
//      untouched -- R10 showed sleeping there hurts the intra-WG chain).
// Protocol recap (R4): wave w owns rows s*32+4w..+3, lane l cols 4l..4l+3.
// NO __syncthreads in the main loop. Intra-WG: per-substep tagged LDS rows
// (vals -> lgkmcnt(0) -> tag; in-order DS => tag-visible implies vals-
// visible), parity double-buffered. Inter-WG: tagged 8-byte {step,value}
// packets, relaxed agent-scope atomics, parity double-buffered. Skew bounded
// to 1 step by the mutual stencil dependency (also proves no overwrite-
// before-read and no deadlock).

#define B_    16
#define T_    256
#define NY    256
#define NP    3
#define NSLAB 8
#define WAVES 8
#define THREADS 512
#define NIF   (NSLAB - 1)

// [side][batch][iface][parity][j][lane]
// side0: slab i's bottom row (wave7 row3) -> consumed by slab i+1 (up ghost)
// side1: slab i+1's top row (wave0 row0)  -> consumed by slab i (down ghost)
__device__ uint64_t g_halo[2][B_][NIF][2][4][64];

__global__ void reset_halo()
{
    const int n = 2 * B_ * NIF * 2 * 4 * 64;
    int i = blockIdx.x * blockDim.x + threadIdx.x;
    if (i < n) (&g_halo[0][0][0][0][0][0])[i] = 0ull;   // tag0,val0 = step-0 data
}

#define PACK(tag, f) (((uint64_t)(uint32_t)(tag) << 32) | (uint64_t)__float_as_uint(f))

#define GPOLL(dst, side, iface, P_, TT) do { \
    uint64_t* gp_ = &g_halo[side][b][iface][P_][0][l]; \
    uint64_t a0_, a1_, a2_, a3_; bool ok_; bool first_ = true; \
    do { \
        if (!first_) __builtin_amdgcn_s_sleep(1); \
        first_ = false; \
        a0_ = __hip_atomic_load(gp_ + 0 * 64, __ATOMIC_RELAXED, __HIP_MEMORY_SCOPE_AGENT); \
        a1_ = __hip_atomic_load(gp_ + 1 * 64, __ATOMIC_RELAXED, __HIP_MEMORY_SCOPE_AGENT); \
        a2_ = __hip_atomic_load(gp_ + 2 * 64, __ATOMIC_RELAXED, __HIP_MEMORY_SCOPE_AGENT); \
        a3_ = __hip_atomic_load(gp_ + 3 * 64, __ATOMIC_RELAXED, __HIP_MEMORY_SCOPE_AGENT); \
        ok_ = ((uint32_t)(a0_ >> 32) == (uint32_t)(TT)) && ((uint32_t)(a1_ >> 32) == (uint32_t)(TT)) \
           && ((uint32_t)(a2_ >> 32) == (uint32_t)(TT)) && ((uint32_t)(a3_ >> 32) == (uint32_t)(TT)); \
    } while (!ok_); \
    dst[0] = __uint_as_float((uint32_t)a0_); dst[1] = __uint_as_float((uint32_t)a1_); \
    dst[2] = __uint_as_float((uint32_t)a2_); dst[3] = __uint_as_float((uint32_t)a3_); \
} while (0)

#define GPUB(side, iface, Q_, TAG1, HROW) do { \
    uint64_t* gp_ = &g_halo[side][b][iface][Q_][0][l]; \
    __hip_atomic_store(gp_ + 0 * 64, PACK(TAG1, HROW[0]), __ATOMIC_RELAXED, __HIP_MEMORY_SCOPE_AGENT); \
    __hip_atomic_store(gp_ + 1 * 64, PACK(TAG1, HROW[1]), __ATOMIC_RELAXED, __HIP_MEMORY_SCOPE_AGENT); \
    __hip_atomic_store(gp_ + 2 * 64, PACK(TAG1, HROW[2]), __ATOMIC_RELAXED, __HIP_MEMORY_SCOPE_AGENT); \
    __hip_atomic_store(gp_ + 3 * 64, PACK(TAG1, HROW[3]), __ATOMIC_RELAXED, __HIP_MEMORY_SCOPE_AGENT); \
} while (0)

// hn = h2 + TC*(h1-h2) + CC*(s4 - 4*h1), written into H2[r] in place.
#define ROWC(H1, H2, r, UPA, DNA) do { \
    float lf_ = __shfl_up(H1[r][3], 1, 64); \
    float rt_ = __shfl_down(H1[r][0], 1, 64); \
    if (l == 0)  lf_ = 0.f; \
    if (l == 63) rt_ = 0.f; \
    _Pragma("unroll") for (int j = 0; j < 4; ++j) { \
        const float lv_ = (j == 0) ? lf_ : H1[r][j - 1]; \
        const float rv_ = (j == 3) ? rt_ : H1[r][j + 1]; \
        const float s4_ = (UPA[j] + DNA[j]) + (lv_ + rv_); \
        const float d_  = H1[r][j] - H2[r][j]; \
        const float e_  = fmaf(-4.0f, H1[r][j], s4_); \
        float v_ = fmaf(CC[r][j], e_, H2[r][j]); \
        v_ = fmaf(TC[r][j], d_, v_); \
        H2[r][j] = v_; \
    } \
} while (0)

#define SRCP(H2, r, TT) do { \
    if (srcHere && src_r == (r)) { \
        _Pragma("unroll") for (int j = 0; j < 4; ++j) \
            if (src_c == j) H2[r][j] += xbuf[TT]; \
    } \
    _Pragma("unroll") for (int qq = 0; qq < NP; ++qq) { \
        if (pHere[qq] && pr[qq] == (r)) { \
            float v_ = 0.f; \
            _Pragma("unroll") for (int j = 0; j < 4; ++j) \
                if (pc[qq] == j) v_ = H2[r][j]; \
            out[((size_t)b * T_ + (TT)) * NP + qq] = v_; \
        } \
    } \
} while (0)

// One substep: H1=h^t, H2=h^{t-1} -> h^{t+1} into H2. P_=t&1, Q_=(t+1)&1.
// Order: poll ghosts -> boundary rows 0,3 -> publish (LDS + global) ->
// interior rows 1,2 (overlap neighbors' consumption).
#define SUB(H1, H2, TT, P_, Q_) do { \
    float gu_[4], gd_[4]; \
    if (w == 0) { \
        if (s == 0) { gu_[0] = gu_[1] = gu_[2] = gu_[3] = 0.f; } \
        else GPOLL(gu_, 0, s - 1, P_, TT); \
    } else { \
        while (__hip_atomic_load(&r3t[w - 1][P_], __ATOMIC_RELAXED, __HIP_MEMORY_SCOPE_WORKGROUP) != (TT)) {} \
        asm volatile("" ::: "memory"); \
        const float4 u4_ = *reinterpret_cast<const float4*>(&r3v[w - 1][P_][y0]); \
        gu_[0] = u4_.x; gu_[1] = u4_.y; gu_[2] = u4_.z; gu_[3] = u4_.w; \
    } \
    if (w == WAVES - 1) { \
        if (s == NSLAB - 1) { gd_[0] = gd_[1] = gd_[2] = gd_[3] = 0.f; } \
        else GPOLL(gd_, 1, s, P_, TT); \
    } else { \
        while (__hip_atomic_load(&r0t[w + 1][P_], __ATOMIC_RELAXED, __HIP_MEMORY_SCOPE_WORKGROUP) != (TT)) {} \
        asm volatile("" ::: "memory"); \
        const float4 d4_ = *reinterpret_cast<const float4*>(&r0v[w + 1][P_][y0]); \
        gd_[0] = d4_.x; gd_[1] = d4_.y; gd_[2] = d4_.z; gd_[3] = d4_.w; \
    } \
    /* boundary rows first */ \
    ROWC(H1, H2, 0, gu_, H1[1]); \
    ROWC(H1, H2, 3, H1[2], gd_); \
    SRCP(H2, 0, TT); \
    SRCP(H2, 3, TT); \
    /* publish: vals, drain DS, then tags (in-order DS => tag implies vals) */ \
    if (w > 0) \
        *reinterpret_cast<float4*>(&r0v[w][Q_][y0]) = make_float4(H2[0][0], H2[0][1], H2[0][2], H2[0][3]); \
    if (w < WAVES - 1) \
        *reinterpret_cast<float4*>(&r3v[w][Q_][y0]) = make_float4(H2[3][0], H2[3][1], H2[3][2], H2[3][3]); \
    asm volatile("s_waitcnt lgkmcnt(0)" ::: "memory"); \
    if (l == 0) { \
        if (w > 0) \
            __hip_atomic_store(&r0t[w][Q_], (TT) + 1, __ATOMIC_RELAXED, __HIP_MEMORY_SCOPE_WORKGROUP); \
        if (w < WAVES - 1) \
            __hip_atomic_store(&r3t[w][Q_], (TT) + 1, __ATOMIC_RELAXED, __HIP_MEMORY_SCOPE_WORKGROUP); \
    } \
    if (w == 0 && s > 0)                 GPUB(1, s - 1, Q_, (TT) + 1, H2[0]); \
    if (w == WAVES - 1 && s < NSLAB - 1) GPUB(0, s,     Q_, (TT) + 1, H2[3]); \
    /* interior rows overlap neighbors' consumption */ \
    ROWC(H1, H2, 1, H1[0], H1[2]); \
    ROWC(H1, H2, 2, H1[1], H1[3]); \
    SRCP(H2, 1, TT); \
    SRCP(H2, 2, TT); \
} while (0)

__launch_bounds__(THREADS, 2)
__global__ void wave_multi(const float* __restrict__ xin,
                           const float* __restrict__ cin,
                           const float* __restrict__ bin,
                           const int* __restrict__ pxp,
                           const int* __restrict__ pyp,
                           const int* __restrict__ sxp,
                           const int* __restrict__ syp,
                           float* __restrict__ out)
{
    const int blk = blockIdx.x;
    // XCD colocation: blk%8 = XCD (round-robin dispatch). Put all slabs of a
    // batch on one XCD: b%8 == blk%8. b = (blk&7) + 8*(blk>>6); s = (blk>>3)&7.
    const int xcd = blk & 7;
    const int m   = blk >> 3;         // 0..15
    const int s   = m & 7;            // slab: rows [s*32, s*32+32)
    const int b   = xcd + ((m >> 3) << 3);  // batch
    const int tid = threadIdx.x;
    const int w = tid >> 6;           // wave 0..7
    const int l = tid & 63;           // lane
    const int r0 = s * 32 + w * 4;    // global row of tile row 0
    const int y0 = l * 4;             // global col of tile col 0

    __shared__ float xbuf[T_];
    __shared__ float r0v[WAVES][2][NY];   // wave w's row0 values, by parity
    __shared__ float r3v[WAVES][2][NY];   // wave w's row3 values, by parity
    __shared__ int   r0t[WAVES][2];       // tags
    __shared__ int   r3t[WAVES][2];

    for (int i = tid; i < WAVES * 2 * NY; i += THREADS) {
        (&r0v[0][0][0])[i] = 0.f;
        (&r3v[0][0][0])[i] = 0.f;
    }
    if (tid < WAVES * 2) {
        const int w_ = tid >> 1, p_ = tid & 1;
        r0t[w_][p_] = (p_ == 0) ? 0 : -1;   // parity0 holds valid step-0 zeros
        r3t[w_][p_] = (p_ == 0) ? 0 : -1;
    }
    if (tid < T_) xbuf[tid] = xin[b * T_ + tid];

    // state + compressed coefficients: TC = 2*c1, CC = c1*(DT^2*c^2)
    // hn = h2 + TC*(h1-h2) + CC*(s4 - 4*h1)   [c1*c2 == 2*c1 - 1]
    float h1[4][4], h2[4][4], TC[4][4], CC[4][4];
#pragma unroll
    for (int r = 0; r < 4; ++r) {
        const float4 cv = *reinterpret_cast<const float4*>(&cin[(r0 + r) * NY + y0]);
        const float4 bv = *reinterpret_cast<const float4*>(&bin[(r0 + r) * NY + y0]);
        const float cvv[4] = {cv.x, cv.y, cv.z, cv.w};
        const float bvv[4] = {bv.x, bv.y, bv.z, bv.w};
#pragma unroll
        for (int j = 0; j < 4; ++j) {
            const float c1  = 1.0f / (1.0f + 0.25f * bvv[j]);
            const float csq = 0.25f * cvv[j] * cvv[j];
            TC[r][j] = 2.0f * c1;
            CC[r][j] = c1 * csq;
            h1[r][j] = 0.f;
            h2[r][j] = 0.f;
        }
    }

    const int sx = sxp[0], sy = syp[0];
    const bool srcHere = (sx >= r0 && sx < r0 + 4 && sy >= y0 && sy < y0 + 4);
    const int  src_r = sx - r0, src_c = sy - y0;
    bool pHere[NP];
    int  pr[NP], pc[NP];
#pragma unroll
    for (int q = 0; q < NP; ++q) {
        const int pxx = pxp[q], pyy = pyp[q];
        pHere[q] = (pxx >= r0 && pxx < r0 + 4 && pyy >= y0 && pyy < y0 + 4);
        pr[q] = pxx - r0;
        pc[q] = pyy - y0;
    }

    __syncthreads();   // the only barrier: LDS init

#pragma unroll 1
    for (int t = 0; t < T_; t += 2) {
        SUB(h1, h2, t,     0, 1);   // h^{t+1} -> h2
        SUB(h2, h1, t + 1, 1, 0);   // h^{t+2} -> h1
    }
}

extern "C" void kernel_launch(void* const* d_in, const int* in_sizes, int n_in,
                              void* d_out, int out_size, void* d_ws, size_t ws_size,
                              hipStream_t stream)
{
    const float* x  = (const float*)d_in[0];
    const float* c  = (const float*)d_in[1];
    const float* bb = (const float*)d_in[2];
    const int*   px = (const int*)d_in[3];
    const int*   py = (const int*)d_in[4];
    const int*   sx = (const int*)d_in[5];
    const int*   sy = (const int*)d_in[6];
    float* out = (float*)d_out;

    const int words = 2 * B_ * NIF * 2 * 4 * 64;
    reset_halo<<<(words + 255) / 256, 256, 0, stream>>>();

    void* args[] = { (void*)&x, (void*)&c, (void*)&bb, (void*)&px, (void*)&py,
                     (void*)&sx, (void*)&sy, (void*)&out };
    hipLaunchCooperativeKernel(reinterpret_cast<void*>(wave_multi),
                               dim3(B_ * NSLAB), dim3(THREADS), args, 0, stream);
}